// Round 3
// baseline (275.295 us; speedup 1.0000x reference)
//
#include <hip/hip_runtime.h>

// B=8192, L=512, P=64, S=32, O=200
// Outputs (flat): [min1, min2, sub_min1, sub_min2, out(8192x200)]
// Strategy: phase1 GEMM x@protoT -> idx/min stats; sort samples by group;
// phase3 per-(group,chunk) GEMM vs subp[g] + stats + register-W GEMV.

#define NL 512
#define NP 64
#define NS 32
#define NO 200
#define NB 8192

// ws layout (4-byte units)
#define WS_SUM    0      // float
#define WS_COLMIN 1      // uint[64]
#define WS_SUBMIN 65     // uint[2048]
#define WS_GRPSUM 2113   // float[64]
#define WS_COUNT  2177   // uint[64]
#define WS_OFFS   2241   // uint[65]
#define WS_SP2    2306   // float[2048]
#define WS_SS     4354   // float[8192]
#define WS_IDX    12546  // int[8192]
#define WS_ORDER  20738  // uint[8192]

__device__ __forceinline__ unsigned encf(float f) {
  unsigned u = __float_as_uint(f);
  return (u & 0x80000000u) ? ~u : (u | 0x80000000u);
}
__device__ __forceinline__ float decf(unsigned m) {
  return __uint_as_float((m & 0x80000000u) ? (m ^ 0x80000000u) : ~m);
}
__device__ __forceinline__ float wred(float v) {
#pragma unroll
  for (int m = 32; m >= 1; m >>= 1) v += __shfl_xor(v, m, 64);
  return v;
}
__device__ __forceinline__ float dot4(const float4& a, const float4& b) {
  return a.x * b.x + a.y * b.y + a.z * b.z + a.w * b.w;
}

// blocks 0..511: sub-proto sq-norms (4 rows/block). block 512: init atomics.
__global__ __launch_bounds__(256) void hier_prep(const float* __restrict__ subp,
                                                 float* __restrict__ ws) {
  if (blockIdx.x == 512) {
    unsigned* wsu = (unsigned*)ws;
    int t = threadIdx.x;
    if (t == 0) ws[WS_SUM] = 0.f;
    if (t < 64) {
      wsu[WS_COLMIN + t] = 0xFFFFFFFFu;
      ws[WS_GRPSUM + t] = 0.f;
      wsu[WS_COUNT + t] = 0u;
    }
    for (int u = t; u < NP * NS; u += 256) wsu[WS_SUBMIN + u] = 0xFFFFFFFFu;
    return;
  }
  const int lane = threadIdx.x & 63;
  const int row = blockIdx.x * 4 + (threadIdx.x >> 6);  // 0..2047
  const float4* rv = (const float4*)(subp + (size_t)row * NL);
  float4 a = rv[2 * lane], b = rv[2 * lane + 1];
  float s = wred(dot4(a, a) + dot4(b, b));
  if (lane == 0) ws[WS_SP2 + row] = s;
}

// 512 blocks x 256 threads: 16 samples x 64 protos. Thread tile 1x4.
__global__ __launch_bounds__(256) void hier_phase1(const float* __restrict__ x,
                                                   const float* __restrict__ proto,
                                                   float* __restrict__ ws) {
  __shared__ float4 xs4[16 * 16];
  __shared__ float4 ps4[64 * 16];
  __shared__ float ss_l[16], pp_l[64];
  __shared__ unsigned colmin_l[64];
  __shared__ float rowmin_l[16];
  __shared__ int rowarg_l[16];
  __shared__ unsigned hist_l[64];

  const int tid = threadIdx.x;
  const int lane = tid & 63;
  const int b0 = blockIdx.x * 16;
  const int ri = tid >> 4;  // 0..15 (row)
  const int ci = tid & 15;  // cols 4ci..4ci+3

  // ||x||^2 per row: 16 threads/row x 8 float4
  {
    const float4* xv = (const float4*)(x + (size_t)(b0 + ri) * NL) + ci * 8;
    float a = 0;
#pragma unroll
    for (int j = 0; j < 8; ++j) a += dot4(xv[j], xv[j]);
#pragma unroll
    for (int m = 1; m <= 8; m <<= 1) a += __shfl_xor(a, m, 64);
    if (ci == 0) { ss_l[ri] = a; ws[WS_SS + b0 + ri] = a; }
  }
  // ||proto||^2: 4 threads/row x 32 float4
  {
    int c = tid >> 2, h = tid & 3;
    const float4* pv = (const float4*)(proto + (size_t)c * NL) + h * 32;
    float a = 0;
#pragma unroll
    for (int j = 0; j < 32; ++j) a += dot4(pv[j], pv[j]);
    a += __shfl_xor(a, 1, 64);
    a += __shfl_xor(a, 2, 64);
    if (h == 0) pp_l[c] = a;
  }
  if (tid < 64) { colmin_l[tid] = 0xFFFFFFFFu; hist_l[tid] = 0u; }

  float acc[4] = {0.f, 0.f, 0.f, 0.f};
  for (int kt = 0; kt < 8; ++kt) {
    __syncthreads();
    {
      int s = tid >> 4, kk = tid & 15;
      xs4[s * 16 + (kk ^ s)] =
          ((const float4*)(x + (size_t)(b0 + s) * NL + kt * 64))[kk];
    }
#pragma unroll
    for (int v = 0; v < 4; ++v) {
      int f = v * 256 + tid;
      int c = f >> 4, kk = f & 15;
      ps4[c * 16 + (kk ^ (c >> 2))] =
          ((const float4*)(proto + (size_t)c * NL + kt * 64))[kk];
    }
    __syncthreads();
#pragma unroll
    for (int kk = 0; kk < 16; ++kk) {
      float4 a0 = xs4[ri * 16 + (kk ^ ri)];
#pragma unroll
      for (int j = 0; j < 4; ++j) {
        float4 b = ps4[(4 * ci + j) * 16 + (kk ^ ci)];
        acc[j] += dot4(a0, b);
      }
    }
  }

  float dv[4];
  float rmin = 1e30f;
  int rarg = 0;
#pragma unroll
  for (int j = 0; j < 4; ++j) {
    dv[j] = ss_l[ri] + pp_l[4 * ci + j] - 2.f * acc[j];
    if (dv[j] < rmin) { rmin = dv[j]; rarg = 4 * ci + j; }
  }
#pragma unroll
  for (int m = 1; m <= 8; m <<= 1) {
    float om = __shfl_xor(rmin, m, 64);
    int oa = __shfl_xor(rarg, m, 64);
    if (om < rmin || (om == rmin && oa < rarg)) { rmin = om; rarg = oa; }
  }
  if (ci == 0) {
    rowmin_l[ri] = rmin;
    rowarg_l[ri] = rarg;
    ((int*)ws)[WS_IDX + b0 + ri] = rarg;
  }
  // col mins over the wave's 4 rows
#pragma unroll
  for (int j = 0; j < 4; ++j) {
    float c = dv[j];
    c = fminf(c, __shfl_xor(c, 16, 64));
    c = fminf(c, __shfl_xor(c, 32, 64));
    if (lane < 16) atomicMin(&colmin_l[4 * ci + j], encf(c));
  }
  __syncthreads();
  if (tid < 64) atomicMin((unsigned*)ws + WS_COLMIN + tid, colmin_l[tid]);
  if (tid < 16) {
    atomicAdd(&hist_l[rowarg_l[tid]], 1u);
    float v = rowmin_l[tid];
#pragma unroll
    for (int m = 1; m <= 8; m <<= 1) v += __shfl_xor(v, m, 64);
    if (tid == 0) atomicAdd(&ws[WS_SUM], v);
  }
  __syncthreads();
  if (tid < 64 && hist_l[tid]) atomicAdd((unsigned*)ws + WS_COUNT + tid, hist_l[tid]);
}

// 1 block: prefix-scan counts -> offsets, then scatter sample ids by group.
__global__ __launch_bounds__(1024) void hier_scan_scatter(float* __restrict__ ws) {
  __shared__ unsigned offs_l[65];
  __shared__ unsigned cursor_l[64];
  const int tid = threadIdx.x;
  if (tid == 0) {
    unsigned run = 0;
    offs_l[0] = 0;
    const unsigned* cnt = (const unsigned*)ws + WS_COUNT;
    for (int g = 0; g < NP; ++g) { run += cnt[g]; offs_l[g + 1] = run; }
  }
  __syncthreads();
  if (tid < 64) cursor_l[tid] = offs_l[tid];
  if (tid < 65) ((unsigned*)ws)[WS_OFFS + tid] = offs_l[tid];
  __syncthreads();
  const int* idx = (const int*)ws + WS_IDX;
  unsigned* order = (unsigned*)ws + WS_ORDER;
  for (int b = tid; b < NB; b += 1024) {
    int g = idx[b];
    unsigned pos = atomicAdd(&cursor_l[g], 1u);
    order[pos] = (unsigned)b;
  }
}

// grid (16, 64): blockIdx.y = group, x = chunk of 32 sorted samples.
__global__ __launch_bounds__(256) void hier_phase3(
    const float* __restrict__ x, const float* __restrict__ subp,
    const float* __restrict__ Wm, const float* __restrict__ bias,
    float* __restrict__ out, float* __restrict__ ws) {
  __shared__ float4 xs4[32 * 16];
  __shared__ float4 sp4[32 * 16];
  __shared__ float dsel_l[32][36];  // row stride 36 floats -> 16B aligned rows
  __shared__ unsigned rows_l[32];
  __shared__ float ss_l[32], sp2_l[32];
  __shared__ unsigned colmin_l[32];
  __shared__ float rowmin_l[32];

  const int tid = threadIdx.x;
  const int lane = tid & 63;
  const int g = blockIdx.y;
  const unsigned off0 = ((const unsigned*)ws)[WS_OFFS + g];
  const unsigned off1 = ((const unsigned*)ws)[WS_OFFS + g + 1];
  if (off0 + blockIdx.x * 32 >= off1) return;

  const int ri = tid >> 4;  // rows 2ri, 2ri+1
  const int ci = tid & 15;  // cols 2ci, 2ci+1

  if (tid < 32) sp2_l[tid] = ws[WS_SP2 + g * NS + tid];

  // hoist expert row into registers (once per block)
  float4 wrow[8];
  float bv = 0.f;
  if (tid < NO) {
    const float4* wr = (const float4*)(Wm + ((size_t)g * NO + tid) * NS);
#pragma unroll
    for (int k = 0; k < 8; ++k) wrow[k] = wr[k];
    bv = bias[g * NO + tid];
  }

  const unsigned* order = (const unsigned*)ws + WS_ORDER;
  const int sa = tid >> 4, kka = tid & 15;  // staging coords

  for (unsigned start = off0 + blockIdx.x * 32; start < off1; start += 16 * 32) {
    const unsigned rem = off1 - start;
    const int m_cnt = (rem < 32u) ? (int)rem : 32;
    if (tid < 32) {
      int mm = (tid < m_cnt) ? tid : (m_cnt - 1);  // pad with duplicate row
      unsigned bm = order[start + mm];
      rows_l[tid] = bm;
      ss_l[tid] = ws[WS_SS + bm];
      colmin_l[tid] = 0xFFFFFFFFu;
    }
    __syncthreads();

    const float* xbase0 = x + (size_t)rows_l[sa] * NL;
    const float* xbase1 = x + (size_t)rows_l[sa + 16] * NL;
    const float* spbase = subp + ((size_t)g * NS + sa) * NL;

    float acc00 = 0, acc01 = 0, acc10 = 0, acc11 = 0;
    for (int kt = 0; kt < 8; ++kt) {
      xs4[sa * 16 + (kka ^ sa)] = ((const float4*)(xbase0 + kt * 64))[kka];
      {
        int s = sa + 16;
        xs4[s * 16 + (kka ^ (s & 15))] = ((const float4*)(xbase1 + kt * 64))[kka];
      }
      sp4[sa * 16 + (kka ^ (sa >> 1))] = ((const float4*)(spbase + kt * 64))[kka];
      {
        int c = sa + 16;
        sp4[c * 16 + (kka ^ (c >> 1))] =
            ((const float4*)(spbase + (size_t)16 * NL + kt * 64))[kka];
      }
      __syncthreads();
#pragma unroll
      for (int kk = 0; kk < 16; ++kk) {
        float4 a0 = xs4[(2 * ri) * 16 + (kk ^ ((2 * ri) & 15))];
        float4 a1 = xs4[(2 * ri + 1) * 16 + (kk ^ ((2 * ri + 1) & 15))];
        float4 b0 = sp4[(2 * ci) * 16 + (kk ^ ci)];
        float4 b1 = sp4[(2 * ci + 1) * 16 + (kk ^ ci)];
        acc00 += dot4(a0, b0);
        acc01 += dot4(a0, b1);
        acc10 += dot4(a1, b0);
        acc11 += dot4(a1, b1);
      }
      __syncthreads();
    }

    float dv00 = ss_l[2 * ri] + sp2_l[2 * ci] - 2.f * acc00;
    float dv01 = ss_l[2 * ri] + sp2_l[2 * ci + 1] - 2.f * acc01;
    float dv10 = ss_l[2 * ri + 1] + sp2_l[2 * ci] - 2.f * acc10;
    float dv11 = ss_l[2 * ri + 1] + sp2_l[2 * ci + 1] - 2.f * acc11;
    dsel_l[2 * ri][2 * ci] = dv00;
    dsel_l[2 * ri][2 * ci + 1] = dv01;
    dsel_l[2 * ri + 1][2 * ci] = dv10;
    dsel_l[2 * ri + 1][2 * ci + 1] = dv11;

    float r0 = fminf(dv00, dv01), r1 = fminf(dv10, dv11);
#pragma unroll
    for (int m = 1; m <= 8; m <<= 1) {
      r0 = fminf(r0, __shfl_xor(r0, m, 64));
      r1 = fminf(r1, __shfl_xor(r1, m, 64));
    }
    if (ci == 0) { rowmin_l[2 * ri] = r0; rowmin_l[2 * ri + 1] = r1; }
    float c0 = fminf(dv00, dv10), c1 = fminf(dv01, dv11);
    c0 = fminf(c0, __shfl_xor(c0, 16, 64));
    c0 = fminf(c0, __shfl_xor(c0, 32, 64));
    c1 = fminf(c1, __shfl_xor(c1, 16, 64));
    c1 = fminf(c1, __shfl_xor(c1, 32, 64));
    if (lane < 16) {
      atomicMin(&colmin_l[2 * ci], encf(c0));
      atomicMin(&colmin_l[2 * ci + 1], encf(c1));
    }
    __syncthreads();
    // padded (duplicate) rows are idempotent for mins; excluded from the sum
    if (tid < 32) atomicMin((unsigned*)ws + WS_SUBMIN + g * NS + tid, colmin_l[tid]);
    if (tid < 32) {
      float v = (tid < m_cnt) ? rowmin_l[tid] : 0.f;
#pragma unroll
      for (int m = 1; m <= 16; m <<= 1) v += __shfl_xor(v, m, 64);
      if (tid == 0) atomicAdd(&ws[WS_GRPSUM + g], v);
    }
    // GEMV from LDS dsel (float4 broadcasts) against register W row
    if (tid < NO) {
      for (int m = 0; m < m_cnt; ++m) {
        const float4* dsm = (const float4*)&dsel_l[m][0];
        float a = bv;
#pragma unroll
        for (int k = 0; k < 8; ++k) {
          float4 d4 = dsm[k];
          a += d4.x * wrow[k].x + d4.y * wrow[k].y + d4.z * wrow[k].z +
               d4.w * wrow[k].w;
        }
        out[(size_t)rows_l[m] * NO + tid] = a;
      }
    }
    __syncthreads();
  }
}

__global__ void hier_final(const float* __restrict__ ws, float* __restrict__ out4) {
  const int lane = threadIdx.x;  // 64 threads
  const unsigned* colmin = (const unsigned*)ws + WS_COLMIN;
  const unsigned* submin = (const unsigned*)ws + WS_SUBMIN;
  const float* grp_sum = ws + WS_GRPSUM;
  const unsigned* counts = (const unsigned*)ws + WS_COUNT;

  float min2 = wred(decf(colmin[lane])) * (1.0f / NP);

  unsigned cnt = counts[lane];
  float s32 = 0.f;
#pragma unroll
  for (int s = 0; s < NS; s++) s32 += decf(submin[lane * NS + s]);
  float sub1 = wred((cnt > 0u) ? s32 * (1.0f / NS) : 0.f) * (1.0f / NP);
  float sub2 = wred((cnt > 0u) ? grp_sum[lane] / (float)cnt : 0.f) * (1.0f / NP);

  if (lane == 0) {
    out4[0] = ws[WS_SUM] * (1.0f / NB);
    out4[1] = min2;
    out4[2] = sub1;
    out4[3] = sub2;
  }
}

extern "C" void kernel_launch(void* const* d_in, const int* in_sizes, int n_in,
                              void* d_out, int out_size, void* d_ws, size_t ws_size,
                              hipStream_t stream) {
  const float* x = (const float*)d_in[0];
  const float* proto = (const float*)d_in[1];
  const float* subp = (const float*)d_in[2];
  const float* Wm = (const float*)d_in[3];
  const float* bias = (const float*)d_in[4];
  float* outf = (float*)d_out;
  float* ws = (float*)d_ws;

  hipLaunchKernelGGL(hier_prep, dim3(513), dim3(256), 0, stream, subp, ws);
  hipLaunchKernelGGL(hier_phase1, dim3(512), dim3(256), 0, stream, x, proto, ws);
  hipLaunchKernelGGL(hier_scan_scatter, dim3(1), dim3(1024), 0, stream, ws);
  hipLaunchKernelGGL(hier_phase3, dim3(16, 64), dim3(256), 0, stream,
                     x, subp, Wm, bias, outf + 4, ws);
  hipLaunchKernelGGL(hier_final, dim3(1), dim3(64), 0, stream, ws, outf);
}